// Round 4
// baseline (1001.873 us; speedup 1.0000x reference)
//
#include <hip/hip_runtime.h>

#define N_NODES 65536
#define G_GRID  32768
#define E_EDGES 600000
#define HD      128

typedef __attribute__((ext_vector_type(8))) short bf8;
typedef __attribute__((ext_vector_type(4))) float f32x4;

__device__ __forceinline__ short f2bf(float f){
  union { float f; unsigned u; } v; v.f = f;
  unsigned r = v.u + 0x7FFFu + ((v.u >> 16) & 1u);
  return (short)(r >> 16);
}

__device__ __forceinline__ bf8 load_pack8(const float* p, float scale){
  float4 u0 = *(const float4*)p;
  float4 u1 = *(const float4*)(p + 4);
  bf8 r;
  r[0]=f2bf(u0.x*scale); r[1]=f2bf(u0.y*scale); r[2]=f2bf(u0.z*scale); r[3]=f2bf(u0.w*scale);
  r[4]=f2bf(u1.x*scale); r[5]=f2bf(u1.y*scale); r[6]=f2bf(u1.z*scale); r[7]=f2bf(u1.w*scale);
  return r;
}

// ---------- weight prep ----------
__global__ void prep_w_k(const float* __restrict__ nmw1, const float* __restrict__ nmw2,
                         const float* __restrict__ emw2, const float* __restrict__ mmw1,
                         const float* __restrict__ mmw2, short* __restrict__ dst)
{
  int i = blockIdx.x*256 + threadIdx.x;  // < 98304
  const float* src; int local; bool k256 = false;
  if      (i < 16384){ src = nmw1; local = i; }
  else if (i < 32768){ src = nmw2; local = i - 16384; }
  else if (i < 49152){ src = emw2; local = i - 32768; }
  else if (i < 81920){ src = mmw1; local = i - 49152; k256 = true; }
  else               { src = mmw2; local = i - 81920; }
  int n, k;
  if (k256){ n = local >> 8; k = local & 255; }
  else     { n = local >> 7; k = local & 127; }
  dst[i] = f2bf(src[k*HD + n]);
}

// ---------- node MLP ----------
__global__ void node_mlp_k(const float* __restrict__ X,
                           const short* __restrict__ w1t, const float* __restrict__ b1,
                           const short* __restrict__ w2t, const float* __restrict__ b2,
                           short* __restrict__ nf)
{
  __shared__ short hid[64][136];
  const int t = threadIdx.x;
  const int wave = t >> 6, lane = t & 63, l15 = lane & 15, q = lane >> 4;
  const int rw = blockIdx.x*64 + wave*16;

  bf8 a[4];
  const float* xr = X + (size_t)(rw + l15)*HD;
  #pragma unroll
  for (int kt=0; kt<4; kt++) a[kt] = load_pack8(xr + kt*32 + q*8, 1.0f);

  #pragma unroll
  for (int ct=0; ct<8; ct++){
    f32x4 acc = {0.f,0.f,0.f,0.f};
    #pragma unroll
    for (int kt=0; kt<4; kt++){
      bf8 b = *(const bf8*)(w1t + (ct*16 + l15)*HD + kt*32 + q*8);
      acc = __builtin_amdgcn_mfma_f32_16x16x32_bf16(a[kt], b, acc, 0, 0, 0);
    }
    float bias = b1[ct*16 + l15];
    #pragma unroll
    for (int r=0;r<4;r++){
      float v = acc[r] + bias;
      v = v / (1.f + __expf(-v));
      hid[wave*16 + q*4 + r][ct*16 + l15] = f2bf(v);
    }
  }
  __syncthreads();

  bf8 a2[4];
  #pragma unroll
  for (int kt=0;kt<4;kt++) a2[kt] = *(const bf8*)&hid[wave*16 + l15][kt*32 + q*8];
  #pragma unroll
  for (int ct=0; ct<8; ct++){
    f32x4 acc = {0.f,0.f,0.f,0.f};
    #pragma unroll
    for (int kt=0;kt<4;kt++){
      bf8 b = *(const bf8*)(w2t + (ct*16 + l15)*HD + kt*32 + q*8);
      acc = __builtin_amdgcn_mfma_f32_16x16x32_bf16(a2[kt], b, acc, 0, 0, 0);
    }
    float bias = b2[ct*16 + l15];
    #pragma unroll
    for (int r=0;r<4;r++)
      nf[(size_t)(rw + q*4 + r)*HD + ct*16 + l15] = f2bf(acc[r] + bias);
  }
}

// ---------- CSR build ----------
__global__ void count_k(const int* __restrict__ eidx, int* __restrict__ counts){
  int e = blockIdx.x*256 + threadIdx.x;
  if (e < E_EDGES) atomicAdd(&counts[eidx[E_EDGES + e]], 1);
}

__global__ void scan_k(const int* __restrict__ counts, int* __restrict__ offs){
  __shared__ int part[1024];
  const int t = threadIdx.x;
  const int base = t*32;
  int loc[32];
  int s = 0;
  #pragma unroll
  for (int i=0;i<32;i++){ loc[i] = s; s += counts[base+i]; }
  part[t] = s;
  __syncthreads();
  for (int off=1; off<1024; off<<=1){
    int v = (t>=off) ? part[t-off] : 0;
    __syncthreads();
    part[t] += v;
    __syncthreads();
  }
  int pre = (t==0) ? 0 : part[t-1];
  #pragma unroll
  for (int i=0;i<32;i++) offs[base+i] = pre + loc[i];
  if (t==1023) offs[G_GRID] = pre + s;
}

__global__ void scatter_k(const int* __restrict__ eidx, const int* __restrict__ offs,
                          int* __restrict__ cursor, int* __restrict__ perm){
  int e = blockIdx.x*256 + threadIdx.x;
  if (e < E_EDGES){
    int g = eidx[E_EDGES + e];
    int slot = offs[g] + atomicAdd(&cursor[g], 1);
    perm[slot] = e;
  }
}

// ---------- fused edge+message, CSR store (no atomics) ----------
__global__ void __launch_bounds__(256, 4)
edge_msg_csr_k(const int* __restrict__ perm, const int* __restrict__ eidx,
               const float* __restrict__ npos, const float* __restrict__ gpos,
               const float* __restrict__ ew1, const float* __restrict__ eb1,
               const short* __restrict__ ew2t, const float* __restrict__ eb2,
               const short* __restrict__ mw1t, const float* __restrict__ mb1,
               const short* __restrict__ mw2t, const float* __restrict__ mb2,
               const short* __restrict__ nf,
               float* __restrict__ msgbuf)
{
  __shared__ float attr[64][8];
  __shared__ int srcs[64];
  __shared__ short hm[64][136];
  __shared__ short efs[64][136];

  const int t = threadIdx.x;
  const int e0 = blockIdx.x*64;
  const int wave = t >> 6, lane = t & 63, l15 = lane & 15, q = lane >> 4;
  const int rl = wave*16;

  if (t < 64){
    int e = perm[e0 + t];
    int s = eidx[e];
    int g = eidx[E_EDGES + e];
    srcs[t] = s;
    attr[t][0] = npos[s*3+0]; attr[t][1] = npos[s*3+1]; attr[t][2] = npos[s*3+2];
    attr[t][3] = gpos[g*3+0]; attr[t][4] = gpos[g*3+1]; attr[t][5] = gpos[g*3+2];
  }
  __syncthreads();

  // nf[src] A-fragment gather, issued early
  bf8 an[4];
  {
    const short* nr = nf + (size_t)srcs[rl + l15]*HD + q*8;
    #pragma unroll
    for (int kt=0;kt<4;kt++) an[kt] = *(const bf8*)(nr + kt*32);
  }

  // edge hidden1 (K=6, fp32 exact)
  {
    int e = t & 63, nb = (t >> 6)*32;
    float a0=attr[e][0], a1=attr[e][1], a2=attr[e][2],
          a3=attr[e][3], a4=attr[e][4], a5=attr[e][5];
    #pragma unroll 8
    for (int j=0;j<32;j++){
      int n = nb + j;
      float v = eb1[n] + a0*ew1[n] + a1*ew1[HD+n] + a2*ew1[2*HD+n]
              + a3*ew1[3*HD+n] + a4*ew1[4*HD+n] + a5*ew1[5*HD+n];
      v = v / (1.f + __expf(-v));
      hm[e][n] = f2bf(v);
    }
  }
  __syncthreads();

  // ef = hm @ em_w2t + eb2 -> efs
  bf8 a[4];
  #pragma unroll
  for (int kt=0;kt<4;kt++) a[kt] = *(const bf8*)&hm[rl + l15][kt*32 + q*8];
  #pragma unroll
  for (int ct=0; ct<8; ct++){
    f32x4 acc = {0.f,0.f,0.f,0.f};
    #pragma unroll
    for (int kt=0;kt<4;kt++){
      bf8 b = *(const bf8*)(ew2t + (ct*16 + l15)*HD + kt*32 + q*8);
      acc = __builtin_amdgcn_mfma_f32_16x16x32_bf16(a[kt], b, acc, 0,0,0);
    }
    float bias = eb2[ct*16 + l15];
    #pragma unroll
    for (int r=0;r<4;r++) efs[rl + q*4 + r][ct*16 + l15] = f2bf(acc[r] + bias);
  }

  // msg hidden = silu(an@W1[0:128] + efs@W1[128:256] + mb1) -> hm
  bf8 ae[4];
  #pragma unroll
  for (int kt=0;kt<4;kt++)
    ae[kt] = *(const bf8*)&efs[rl + l15][kt*32 + q*8];
  #pragma unroll
  for (int ct=0; ct<8; ct++){
    f32x4 acc = {0.f,0.f,0.f,0.f};
    #pragma unroll
    for (int kt=0;kt<4;kt++){
      bf8 b = *(const bf8*)(mw1t + (ct*16 + l15)*256 + kt*32 + q*8);
      acc = __builtin_amdgcn_mfma_f32_16x16x32_bf16(an[kt], b, acc, 0,0,0);
    }
    #pragma unroll
    for (int kt=0;kt<4;kt++){
      bf8 b = *(const bf8*)(mw1t + (ct*16 + l15)*256 + 128 + kt*32 + q*8);
      acc = __builtin_amdgcn_mfma_f32_16x16x32_bf16(ae[kt], b, acc, 0,0,0);
    }
    float bias = mb1[ct*16 + l15];
    #pragma unroll
    for (int r=0;r<4;r++){
      float v = acc[r] + bias;
      v = v / (1.f + __expf(-v));
      hm[rl + q*4 + r][ct*16 + l15] = f2bf(v);
    }
  }

  // msg = hm @ mm_w2t + mb2 -> coalesced store into msgbuf[sorted slot]
  bf8 am[4];
  #pragma unroll
  for (int kt=0;kt<4;kt++) am[kt] = *(const bf8*)&hm[rl + l15][kt*32 + q*8];
  #pragma unroll
  for (int ct=0; ct<8; ct++){
    f32x4 acc = {0.f,0.f,0.f,0.f};
    #pragma unroll
    for (int kt=0;kt<4;kt++){
      bf8 b = *(const bf8*)(mw2t + (ct*16 + l15)*HD + kt*32 + q*8);
      acc = __builtin_amdgcn_mfma_f32_16x16x32_bf16(am[kt], b, acc, 0,0,0);
    }
    float bias = mb2[ct*16 + l15];
    int col = ct*16 + l15;
    #pragma unroll
    for (int r=0;r<4;r++)
      msgbuf[(size_t)(e0 + rl + q*4 + r)*HD + col] = acc[r] + bias;
  }
}

// ---------- segment mean over sorted msg rows ----------
__global__ void agg_k(const float* __restrict__ msgbuf, const int* __restrict__ offs,
                      const int* __restrict__ counts, float* __restrict__ agg)
{
  int g = blockIdx.x*4 + (threadIdx.x >> 6);
  int lane = threadIdx.x & 63;
  int s = offs[g], e = offs[g+1];
  float ax = 0.f, ay = 0.f;
  const float* p = msgbuf + (size_t)s*HD + lane*2;
  for (int r=s; r<e; r++, p+=HD){
    float2 v = *(const float2*)p;
    ax += v.x; ay += v.y;
  }
  float rcp = 1.0f / fmaxf((float)counts[g], 1.0f);
  float2 o; o.x = ax*rcp; o.y = ay*rcp;
  *(float2*)&agg[(size_t)g*HD + lane*2] = o;
}

// ---------- fallback: atomic edge+message (round-3 path) ----------
__global__ void __launch_bounds__(256, 4)
edge_msg_atomic_k(const int* __restrict__ eidx,
           const float* __restrict__ npos, const float* __restrict__ gpos,
           const float* __restrict__ ew1, const float* __restrict__ eb1,
           const short* __restrict__ ew2t, const float* __restrict__ eb2,
           const short* __restrict__ mw1t, const float* __restrict__ mb1,
           const short* __restrict__ mw2t, const float* __restrict__ mb2,
           const short* __restrict__ nf,
           float* __restrict__ agg, float* __restrict__ cnt)
{
  __shared__ float attr[64][8];
  __shared__ int srcs[64], tgts[64];
  __shared__ short hm[64][136];
  __shared__ short efs[64][136];

  const int t = threadIdx.x;
  const int e0 = blockIdx.x*64;
  const int wave = t >> 6, lane = t & 63, l15 = lane & 15, q = lane >> 4;
  const int rl = wave*16;

  if (t < 64){
    int e = e0 + t;
    int s = eidx[e];
    int g = eidx[E_EDGES + e];
    srcs[t] = s; tgts[t] = g;
    attr[t][0] = npos[s*3+0]; attr[t][1] = npos[s*3+1]; attr[t][2] = npos[s*3+2];
    attr[t][3] = gpos[g*3+0]; attr[t][4] = gpos[g*3+1]; attr[t][5] = gpos[g*3+2];
    atomicAdd(&cnt[g], 1.0f);
  }
  __syncthreads();

  bf8 an[4];
  {
    const short* nr = nf + (size_t)srcs[rl + l15]*HD + q*8;
    #pragma unroll
    for (int kt=0;kt<4;kt++) an[kt] = *(const bf8*)(nr + kt*32);
  }
  {
    int e = t & 63, nb = (t >> 6)*32;
    float a0=attr[e][0], a1=attr[e][1], a2=attr[e][2],
          a3=attr[e][3], a4=attr[e][4], a5=attr[e][5];
    #pragma unroll 8
    for (int j=0;j<32;j++){
      int n = nb + j;
      float v = eb1[n] + a0*ew1[n] + a1*ew1[HD+n] + a2*ew1[2*HD+n]
              + a3*ew1[3*HD+n] + a4*ew1[4*HD+n] + a5*ew1[5*HD+n];
      v = v / (1.f + __expf(-v));
      hm[e][n] = f2bf(v);
    }
  }
  __syncthreads();

  bf8 a[4];
  #pragma unroll
  for (int kt=0;kt<4;kt++) a[kt] = *(const bf8*)&hm[rl + l15][kt*32 + q*8];
  #pragma unroll
  for (int ct=0; ct<8; ct++){
    f32x4 acc = {0.f,0.f,0.f,0.f};
    #pragma unroll
    for (int kt=0;kt<4;kt++){
      bf8 b = *(const bf8*)(ew2t + (ct*16 + l15)*HD + kt*32 + q*8);
      acc = __builtin_amdgcn_mfma_f32_16x16x32_bf16(a[kt], b, acc, 0,0,0);
    }
    float bias = eb2[ct*16 + l15];
    #pragma unroll
    for (int r=0;r<4;r++) efs[rl + q*4 + r][ct*16 + l15] = f2bf(acc[r] + bias);
  }

  bf8 ae[4];
  #pragma unroll
  for (int kt=0;kt<4;kt++)
    ae[kt] = *(const bf8*)&efs[rl + l15][kt*32 + q*8];
  #pragma unroll
  for (int ct=0; ct<8; ct++){
    f32x4 acc = {0.f,0.f,0.f,0.f};
    #pragma unroll
    for (int kt=0;kt<4;kt++){
      bf8 b = *(const bf8*)(mw1t + (ct*16 + l15)*256 + kt*32 + q*8);
      acc = __builtin_amdgcn_mfma_f32_16x16x32_bf16(an[kt], b, acc, 0,0,0);
    }
    #pragma unroll
    for (int kt=0;kt<4;kt++){
      bf8 b = *(const bf8*)(mw1t + (ct*16 + l15)*256 + 128 + kt*32 + q*8);
      acc = __builtin_amdgcn_mfma_f32_16x16x32_bf16(ae[kt], b, acc, 0,0,0);
    }
    float bias = mb1[ct*16 + l15];
    #pragma unroll
    for (int r=0;r<4;r++){
      float v = acc[r] + bias;
      v = v / (1.f + __expf(-v));
      hm[rl + q*4 + r][ct*16 + l15] = f2bf(v);
    }
  }

  bf8 am[4];
  #pragma unroll
  for (int kt=0;kt<4;kt++) am[kt] = *(const bf8*)&hm[rl + l15][kt*32 + q*8];
  int tg[4];
  #pragma unroll
  for (int r=0;r<4;r++) tg[r] = tgts[rl + q*4 + r];
  #pragma unroll
  for (int ct=0; ct<8; ct++){
    f32x4 acc = {0.f,0.f,0.f,0.f};
    #pragma unroll
    for (int kt=0;kt<4;kt++){
      bf8 b = *(const bf8*)(mw2t + (ct*16 + l15)*HD + kt*32 + q*8);
      acc = __builtin_amdgcn_mfma_f32_16x16x32_bf16(am[kt], b, acc, 0,0,0);
    }
    float bias = mb2[ct*16 + l15];
    int col = ct*16 + l15;
    #pragma unroll
    for (int r=0;r<4;r++)
      atomicAdd(&agg[(size_t)tg[r]*HD + col], acc[r] + bias);
  }
}

// ---------- update MLP, fp32 (accuracy anchor). cnt==nullptr -> agg pre-divided ----------
__global__ void update_mlp_k(const float* __restrict__ agg, const float* __restrict__ cnt,
                             const float* __restrict__ w1, const float* __restrict__ b1,
                             const float* __restrict__ w2, const float* __restrict__ b2,
                             float* __restrict__ out)
{
  __shared__ float xs[32][129];
  __shared__ float hs[32][129];
  const int t = threadIdx.x;
  const int rb = blockIdx.x*32;
  {
    int e = t >> 3, c0 = (t & 7)*16;
    float rcp = 1.0f;
    if (cnt) rcp = 1.0f / fmaxf(cnt[rb + e], 1.0f);
    const float* p = agg + (size_t)(rb + e)*HD + c0;
    #pragma unroll
    for (int i=0;i<16;i++) xs[e][c0+i] = p[i]*rcp;
  }
  __syncthreads();
  int e = t >> 3, n0 = (t & 7)*16;
  float acc[16];
  #pragma unroll
  for (int j=0;j<16;j++) acc[j] = b1[n0+j];
  for (int k=0;k<HD;k++){
    float x = xs[e][k];
    const float* wr = w1 + k*HD + n0;
    #pragma unroll
    for (int j=0;j<16;j++) acc[j] += x * wr[j];
  }
  #pragma unroll
  for (int j=0;j<16;j++){
    float v = acc[j];
    hs[e][n0+j] = v / (1.f + expf(-v));
  }
  __syncthreads();
  #pragma unroll
  for (int j=0;j<16;j++) acc[j] = b2[n0+j];
  for (int k=0;k<HD;k++){
    float x = hs[e][k];
    const float* wr = w2 + k*HD + n0;
    #pragma unroll
    for (int j=0;j<16;j++) acc[j] += x * wr[j];
  }
  float* op = out + (size_t)(rb + e)*HD + n0;
  #pragma unroll
  for (int j=0;j<16;j++) op[j] = acc[j];
}

extern "C" void kernel_launch(void* const* d_in, const int* in_sizes, int n_in,
                              void* d_out, int out_size, void* d_ws, size_t ws_size,
                              hipStream_t stream)
{
  const float* node_features = (const float*)d_in[0];
  const float* node_pos      = (const float*)d_in[1];
  const float* grid_pos      = (const float*)d_in[2];
  const int*   edge_index    = (const int*)d_in[3];
  const float* nm_w1 = (const float*)d_in[4];
  const float* nm_b1 = (const float*)d_in[5];
  const float* nm_w2 = (const float*)d_in[6];
  const float* nm_b2 = (const float*)d_in[7];
  const float* em_w1 = (const float*)d_in[8];
  const float* em_b1 = (const float*)d_in[9];
  const float* em_w2 = (const float*)d_in[10];
  const float* em_b2 = (const float*)d_in[11];
  const float* mm_w1 = (const float*)d_in[12];
  const float* mm_b1 = (const float*)d_in[13];
  const float* mm_w2 = (const float*)d_in[14];
  const float* mm_b2 = (const float*)d_in[15];
  const float* um_w1 = (const float*)d_in[16];
  const float* um_b1 = (const float*)d_in[17];
  const float* um_w2 = (const float*)d_in[18];
  const float* um_b2 = (const float*)d_in[19];
  float* out = (float*)d_out;

  char* ws = (char*)d_ws;
  // layout
  short* nf    = (short*)ws;                              // 16 MB bf16 [N,128]
  float* agg   = (float*)(ws + 16777216ull);              // 16 MB f32 [G,128]
  int*   counts= (int*)  (ws + 33554432ull);              // 128 KB
  int*   cursor= (int*)  (ws + 33685504ull);              // 128 KB
  int*   offs  = (int*)  (ws + 33816576ull);              // 128 KB + pad
  short* wts   = (short*)(ws + 33948160ull);              // 192 KB
  float* cntf  = (float*)(ws + 34144768ull);              // 128 KB (fallback)
  int*   perm  = (int*)  (ws + 34275840ull);              // 2.4 MB
  float* msgbuf= (float*)(ws + 36675840ull);              // 307.2 MB
  const size_t WS_NEED = 36675840ull + (size_t)E_EDGES*HD*4;

  short* nmw1t = wts;
  short* nmw2t = wts + 16384;
  short* emw2t = wts + 32768;
  short* mmw1t = wts + 49152;
  short* mmw2t = wts + 81920;

  const bool csr = (ws_size >= WS_NEED);

  prep_w_k<<<384, 256, 0, stream>>>(nm_w1, nm_w2, em_w2, mm_w1, mm_w2, wts);
  node_mlp_k<<<N_NODES/64, 256, 0, stream>>>(node_features, nmw1t, nm_b1, nmw2t, nm_b2, nf);

  if (csr){
    (void)hipMemsetAsync(ws + 33554432ull, 0, 262144, stream);  // counts + cursor
    count_k<<<(E_EDGES+255)/256, 256, 0, stream>>>(edge_index, counts);
    scan_k<<<1, 1024, 0, stream>>>(counts, offs);
    scatter_k<<<(E_EDGES+255)/256, 256, 0, stream>>>(edge_index, offs, cursor, perm);
    edge_msg_csr_k<<<E_EDGES/64, 256, 0, stream>>>(perm, edge_index, node_pos, grid_pos,
        em_w1, em_b1, emw2t, em_b2, mmw1t, mm_b1, mmw2t, mm_b2, nf, msgbuf);
    agg_k<<<G_GRID/4, 256, 0, stream>>>(msgbuf, offs, counts, agg);
    update_mlp_k<<<G_GRID/32, 256, 0, stream>>>(agg, (const float*)nullptr,
        um_w1, um_b1, um_w2, um_b2, out);
  } else {
    (void)hipMemsetAsync(agg, 0, 16777216, stream);
    (void)hipMemsetAsync(cntf, 0, 131072, stream);
    edge_msg_atomic_k<<<E_EDGES/64, 256, 0, stream>>>(edge_index, node_pos, grid_pos,
        em_w1, em_b1, emw2t, em_b2, mmw1t, mm_b1, mmw2t, mm_b2, nf, agg, cntf);
    update_mlp_k<<<G_GRID/32, 256, 0, stream>>>(agg, cntf, um_w1, um_b1, um_w2, um_b2, out);
  }
}